// Round 16
// baseline (378.895 us; speedup 1.0000x reference)
//
#include <hip/hip_runtime.h>

typedef unsigned short u16;
typedef unsigned int   u32;
typedef __attribute__((ext_vector_type(8))) _Float16 f16x8;
typedef __attribute__((ext_vector_type(2))) float f32x2;
typedef __attribute__((ext_vector_type(4))) float f32x4;
typedef __attribute__((ext_vector_type(16))) float f32x16;
typedef __attribute__((ext_vector_type(4))) unsigned int u32x4;

constexpr int B_  = 4;
constexpr int C0  = 128;
constexpr int C1  = 32;
constexpr int H_  = 96;
constexpr int W_  = 96;
constexpr int HW  = H_ * W_;        // 9216
constexpr int PT  = 64;
constexpr int TPB = HW / PT;        // 144
constexpr int NTILE = B_ * TPB;     // 576

__device__ inline u16 f2h(float f) {
    _Float16 h = (_Float16)f;
    return __builtin_bit_cast(u16, h);
}

// ---------------------------------------------------------------------------
// Weight prep.  Deform weights split hi/lo f16 AND written as the exact
// XOR-swizzled LDS image per K-half (see k_deform12).
__global__ __launch_bounds__(256) void k_prep(
    const float* __restrict__ w_off,
    const float* __restrict__ wd1,  const float* __restrict__ wd2,
    const float* __restrict__ s1c0, const float* __restrict__ s1h0,
    const float* __restrict__ s2c0, const float* __restrict__ s2h0,
    const float* __restrict__ s1c1, const float* __restrict__ s1h1,
    const float* __restrict__ s2c1, const float* __restrict__ s2h1,
    float* __restrict__ wofft, u16* __restrict__ wdsh, u16* __restrict__ wdsl,
    u16* __restrict__ w0h,     u16* __restrict__ w1h)
{
    int t = blockIdx.x * 256 + threadIdx.x;
    if (t < C0 * 18 * 9) {
        int c = t / 162, r = t % 162, o = r / 9, tap = r % 9;
        wofft[t] = w_off[(o * C0 + c) * 9 + tap];
    }
    if (t < 2 * 9 * C0 * C0) {
        int d = t / (9 * C0 * C0), r = t % (9 * C0 * C0);
        int k = r / (C0 * C0), r2 = r % (C0 * C0), o = r2 / C0, c = r2 % C0;
        const float* wsrc = d ? wd2 : wd1;
        float wv = wsrc[(o * C0 + c) * 9 + k];
        _Float16 hi = (_Float16)wv;
        float rr = wv - (float)hi;
        int kh = c >> 6, cc = c & 63;
        size_t dst = (((size_t)(d * 9 + k) * 2 + kh) * 8192)
                   + o * 64 + (((cc & 56) ^ ((o & 7) << 3)) | (cc & 7));
        wdsh[dst] = __builtin_bit_cast(u16, hi);
        wdsl[dst] = f2h(rr);
    }
    if (t < 4 * C0 * C1) {
        int m = t / (C0 * C1), i = t % (C0 * C1);
        const float* s = (m == 0) ? s1c0 : (m == 1) ? s1h0 : (m == 2) ? s2c0 : s2h0;
        w0h[t] = f2h(s[i]);
    }
    if (t < 4 * C0 * C0) {
        int m = t / (C0 * C0), i = t % (C0 * C0);
        const float* s = (m == 0) ? s1c1 : (m == 1) ? s1h1 : (m == 2) ? s2c1 : s2h1;
        w1h[t] = f2h(s[i]);
    }
}

// ---------------------------------------------------------------------------
// Offset conv: 3x3, 128 -> 18 (f32, round-1 proven)
__global__ __launch_bounds__(256) void k_conv_off(
    const float* __restrict__ x0, const float* __restrict__ wofft,
    const float* __restrict__ boff, float* __restrict__ off)
{
    int bx = blockIdx.x;
    int b  = bx / TPB;
    int p0 = (bx % TPB) * PT;
    int tid = threadIdx.x;
    int p   = tid & 63;
    int cq  = __builtin_amdgcn_readfirstlane(tid >> 6);
    int pos = p0 + p;
    int h = pos / W_, w = pos % W_;

    float acc[18];
#pragma unroll
    for (int o = 0; o < 18; ++o) acc[o] = 0.f;

    for (int cc = 0; cc < 32; ++cc) {
        int c = cq * 32 + cc;
        const float* xb = x0 + ((size_t)(b * C0 + c)) * HW;
        float v[9];
#pragma unroll
        for (int t = 0; t < 9; ++t) {
            int dy = t / 3 - 1, dx = t % 3 - 1;
            int hy = h + dy, wx = w + dx;
            bool ok = (hy >= 0) & (hy < H_) & (wx >= 0) & (wx < W_);
            v[t] = ok ? xb[hy * W_ + wx] : 0.f;
        }
        const float* wr = wofft + c * 162;
#pragma unroll
        for (int o = 0; o < 18; ++o)
#pragma unroll
            for (int t = 0; t < 9; ++t)
                acc[o] = fmaf(wr[o * 9 + t], v[t], acc[o]);
    }

    __shared__ float red[4][18][PT];
#pragma unroll
    for (int o = 0; o < 18; ++o) red[cq][o][p] = acc[o];
    __syncthreads();
    for (int idx = tid; idx < 18 * PT; idx += 256) {
        int o = idx / PT, pp = idx % PT;
        float s = red[0][o][pp] + red[1][o][pp] + red[2][o][pp] + red[3][o][pp]
                + boff[o];
        off[((size_t)(b * 18 + o)) * HW + p0 + pp] = s;
    }
}

// ---------------------------------------------------------------------------
// Fused SFT via MFMA (round-11 version; proven absmax 0.0156)
template <int XSRC>
__global__ __launch_bounds__(512, 6) void k_sft_mma(
    const float* __restrict__ xf,     // XSRC==0
    const float* __restrict__ xT,     // XSRC==1
    const float* __restrict__ x1,
    const u16* __restrict__ w0s, const u16* __restrict__ w0h,   // [128 hid][32 ch]
    const u16* __restrict__ w1s, const u16* __restrict__ w1h,   // [128 out][128 hid]
    const float* __restrict__ b0s, const float* __restrict__ b0h,
    const float* __restrict__ b1s, const float* __restrict__ b1h,
    float* __restrict__ outT)         // [B,HW,128]
{
    __shared__ __align__(16) u16 x1t[64 * 32];
    __shared__ __align__(16) u16 hidt[2][64 * 128];

    int bx = blockIdx.x, b = bx / TPB, p0 = (bx % TPB) * PT;
    int tid = threadIdx.x, l = tid & 63;
    int w = __builtin_amdgcn_readfirstlane(tid >> 6);
    f32x4 zz = {0.f, 0.f, 0.f, 0.f};

    for (int i = tid; i < C1 * PT; i += 512) {
        int ch = i >> 6, pos = i & 63;
        float v = x1[((size_t)(b * C1 + ch)) * HW + p0 + pos];
        x1t[pos * 32 + (ch ^ ((pos & 3) << 3))] = f2h(v);
    }
    __syncthreads();

    {   // hidden GEMM (K=32)
        int mt = w & 3, br = w >> 2;
        int pos = mt * 16 + (l & 15);
        int koff = (l >> 4) * 8;
        f16x8 a = *(const f16x8*)&x1t[pos * 32 + (koff ^ ((pos & 3) << 3))];
        const u16* w0 = br ? w0h : w0s;
        const float* bb = br ? b0h : b0s;
        u16* hrow = hidt[br];
#pragma unroll
        for (int nt = 0; nt < 8; ++nt) {
            int n = nt * 16 + (l & 15);
            f16x8 bfr = *(const f16x8*)&w0[n * 32 + koff];
            f32x4 h = __builtin_amdgcn_mfma_f32_16x16x32_f16(a, bfr, zz, 0, 0, 0);
            float bv = bb[n];
#pragma unroll
            for (int r = 0; r < 4; ++r) {
                float hv = h[r] + bv;
                hv = hv > 0.f ? hv : 0.1f * hv;
                int prow = mt * 16 + (l >> 4) * 4 + r;
                hrow[prow * 128 + (n ^ ((prow & 7) << 3))] = f2h(hv);
            }
        }
    }
    __syncthreads();

    f32x4 accS[4], accH[4];
#pragma unroll
    for (int nt = 0; nt < 4; ++nt) { accS[nt] = zz; accH[nt] = zz; }
    int mt = w & 3, nh = w >> 2;
    int pos = mt * 16 + (l & 15);
#pragma unroll
    for (int ks = 0; ks < 4; ++ks) {
        int kb = ks * 32 + (l >> 4) * 8;
        f16x8 aS = *(const f16x8*)&hidt[0][pos * 128 + (kb ^ ((pos & 7) << 3))];
        f16x8 aH = *(const f16x8*)&hidt[1][pos * 128 + (kb ^ ((pos & 7) << 3))];
#pragma unroll
        for (int nt = 0; nt < 4; ++nt) {
            int n = nh * 64 + nt * 16 + (l & 15);
            f16x8 bS = *(const f16x8*)&w1s[n * 128 + kb];
            f16x8 bH = *(const f16x8*)&w1h[n * 128 + kb];
            accS[nt] = __builtin_amdgcn_mfma_f32_16x16x32_f16(aS, bS, accS[nt], 0, 0, 0);
            accH[nt] = __builtin_amdgcn_mfma_f32_16x16x32_f16(aH, bH, accH[nt], 0, 0, 0);
        }
    }

#pragma unroll
    for (int nt = 0; nt < 4; ++nt) {
        int n = nh * 64 + nt * 16 + (l & 15);
        float scb = b1s[n], shb = b1h[n];
        float xv[4];
        if (XSRC == 0) {
            const float* xp = xf + ((size_t)(b * C0 + n)) * HW + p0 + mt * 16 + (l >> 4) * 4;
            f32x4 x4 = *(const f32x4*)xp;
#pragma unroll
            for (int r = 0; r < 4; ++r) xv[r] = x4[r];
        } else {
#pragma unroll
            for (int r = 0; r < 4; ++r)
                xv[r] = xT[((size_t)(b * HW + p0 + mt * 16 + (l >> 4) * 4 + r)) * C0 + n];
        }
#pragma unroll
        for (int r = 0; r < 4; ++r) {
            float scale = accS[nt][r] + scb + 1.f;
            float shift = accH[nt][r] + shb;
            outT[((size_t)(b * HW + p0 + mt * 16 + (l >> 4) * 4 + r)) * C0 + n]
                = xv[r] * scale + shift;
        }
    }
}

// ---------------------------------------------------------------------------
// Deformable conv 3x3, split-f16 3-term via 32x32x16 MFMA, v8.1:
//  - B staged via global_load_lds from PRE-SWIZZLED weight image
//  - counted vmcnt(32) in steady state (4 B-loads + 32 gathers outstanding);
//    TAIL PEELED: k=8 uses vmcnt(0) (round-15 race fix)
//  - A XOR-swizzled, VALU-committed; lgkm-only barriers in-loop
template <int MODE>
__global__ __launch_bounds__(512, 4) void k_deform12(
    const float* __restrict__ srcT,  // [B,HW,128] f32
    const float* __restrict__ off,   // [B,18,HW]
    const u16* __restrict__ whiS,    // swizzled image [9][2][8192] f16 hi
    const u16* __restrict__ wloS,    // swizzled image [9][2][8192] f16 lo
    const float* __restrict__ bias,
    const float* __restrict__ x0,
    float* __restrict__ outF,        // MODE 1
    float* __restrict__ outT)        // MODE 0
{
    __shared__ __align__(16) u16   smem[16384 + 16384 + 2304];
    __shared__ __align__(16) float cwt[9 * 64 * 2];
    u16* a_hi = smem;                 // [64][128] swz
    u16* a_lo = smem + 8192;
    u16* b_hi = smem + 16384;         // [128][64] swz image (one K-half)
    u16* b_lo = smem + 16384 + 8192;
    u16* cidx = smem + 32768;

    int bx = blockIdx.x;
    bx = (bx & 7) * (NTILE / 8) + (bx >> 3);            // XCD swizzle
    int b = bx / TPB, p0 = (bx % TPB) * PT;
    int tid = threadIdx.x, l = tid & 63;
    int w = __builtin_amdgcn_readfirstlane(tid >> 6);
    int mh = w & 1, ng = w >> 1;
    int lr = l & 31, ksel = l >> 5;

    // Phase 0: coords for all 9 taps
    for (int e = tid; e < 9 * 64; e += 512) {
        int k = e >> 6, pp = e & 63;
        int pos = p0 + pp, h = pos / W_, wc = pos % W_;
        float dy = off[((size_t)(b * 18 + 2 * k)) * HW + pos];
        float dx = off[((size_t)(b * 18 + 2 * k + 1)) * HW + pos];
        float py = dy + (float)(h + k / 3 - 1);
        float px = dx + (float)(wc + k % 3 - 1);
        float yf = floorf(py), xf = floorf(px);
        int y0 = (int)yf, x0i = (int)xf;
        cwt[e * 2]     = py - yf;
        cwt[e * 2 + 1] = px - xf;
        int iy0 = min(max(y0, 0), H_ - 1),     iy1 = min(max(y0 + 1, 0), H_ - 1);
        int ix0 = min(max(x0i, 0), W_ - 1),    ix1 = min(max(x0i + 1, 0), W_ - 1);
        bool vy0 = (y0 >= 0) & (y0 < H_),      vy1 = (y0 + 1 >= 0) & (y0 + 1 < H_);
        bool vx0 = (x0i >= 0) & (x0i < W_),    vx1 = (x0i + 1 >= 0) & (x0i + 1 < W_);
        cidx[e * 4 + 0] = (u16)(iy0 * W_ + ix0) | ((vy0 & vx0) ? 0x8000 : 0);
        cidx[e * 4 + 1] = (u16)(iy0 * W_ + ix1) | ((vy0 & vx1) ? 0x8000 : 0);
        cidx[e * 4 + 2] = (u16)(iy1 * W_ + ix0) | ((vy1 & vx0) ? 0x8000 : 0);
        cidx[e * 4 + 3] = (u16)(iy1 * W_ + ix1) | ((vy1 & vx1) ? 0x8000 : 0);
    }
    __syncthreads();

    f32x16 acc;
#pragma unroll
    for (int i = 0; i < 16; ++i) acc[i] = 0.f;

    const float* lbase = srcT + (size_t)b * HW * C0 + 2 * l;
    f32x2 gv[8][4];                                     // in-flight A corners

#define GLOADB(KK, KH)                                                        \
    {                                                                         \
        const u16* sh = whiS + (((size_t)(KK) * 2 + (KH)) * 8192);            \
        const u16* sl = wloS + (((size_t)(KK) * 2 + (KH)) * 8192);            \
        _Pragma("unroll")                                                     \
        for (int i = 0; i < 2; ++i) {                                         \
            __builtin_amdgcn_global_load_lds(                                 \
                (const __attribute__((address_space(1))) unsigned int*)(sh + (tid + i * 512) * 8), \
                (__attribute__((address_space(3))) unsigned int*)((char*)b_hi + ((tid & ~63) + i * 512) * 16), \
                16, 0, 0);                                                    \
            __builtin_amdgcn_global_load_lds(                                 \
                (const __attribute__((address_space(1))) unsigned int*)(sl + (tid + i * 512) * 8), \
                (__attribute__((address_space(3))) unsigned int*)((char*)b_lo + ((tid & ~63) + i * 512) * 16), \
                16, 0, 0);                                                    \
        }                                                                     \
    }

#define ISSUE_G(KK)                                                           \
    {                                                                         \
        int ek = (KK) * 64 + w * 8;                                           \
        _Pragma("unroll")                                                     \
        for (int i = 0; i < 8; ++i) {                                         \
            int e = ek + i;                                                   \
            u32 c01 = *(const u32*)&cidx[e * 4];                              \
            u32 c23 = *(const u32*)&cidx[e * 4 + 2];                          \
            gv[i][0] = *(const f32x2*)(lbase + (size_t)(c01 & 0x3fffu) * C0); \
            gv[i][1] = *(const f32x2*)(lbase + (size_t)((c01 >> 16) & 0x3fffu) * C0); \
            gv[i][2] = *(const f32x2*)(lbase + (size_t)(c23 & 0x3fffu) * C0); \
            gv[i][3] = *(const f32x2*)(lbase + (size_t)((c23 >> 16) & 0x3fffu) * C0); \
        }                                                                     \
    }

#define COMMIT_A(KK)                                                          \
    {                                                                         \
        int ek = (KK) * 64 + w * 8;                                           \
        _Pragma("unroll")                                                     \
        for (int i = 0; i < 8; ++i) {                                         \
            int e = ek + i, pp = w * 8 + i;                                   \
            u32 c01 = *(const u32*)&cidx[e * 4];                              \
            u32 c23 = *(const u32*)&cidx[e * 4 + 2];                          \
            float wy = cwt[e * 2], wx = cwt[e * 2 + 1];                       \
            float aa  = wy * wx;                                              \
            float w11 = (c23 & 0x80000000u) ? aa : 0.f;                       \
            float w10 = (c23 & 0x8000u) ? (wy - aa) : 0.f;                    \
            float w01 = (c01 & 0x80000000u) ? (wx - aa) : 0.f;                \
            float w00 = (c01 & 0x8000u) ? (1.f - wy - wx + aa) : 0.f;         \
            float s0 = gv[i][0][0] * w00 + gv[i][1][0] * w01                  \
                     + gv[i][2][0] * w10 + gv[i][3][0] * w11;                 \
            float s1 = gv[i][0][1] * w00 + gv[i][1][1] * w01                  \
                     + gv[i][2][1] * w10 + gv[i][3][1] * w11;                 \
            _Float16 h0 = (_Float16)s0, h1 = (_Float16)s1;                    \
            float r0 = s0 - (float)h0, r1 = s1 - (float)h1;                   \
            u32 hv = (u32)__builtin_bit_cast(u16, h0)                         \
                   | ((u32)__builtin_bit_cast(u16, h1) << 16);                \
            u32 lv = (u32)f2h(r0) | ((u32)f2h(r1) << 16);                     \
            int ci = (2 * l) ^ ((pp & 7) << 3);                               \
            *(u32*)&a_hi[pp * 128 + ci] = hv;                                 \
            *(u32*)&a_lo[pp * 128 + ci] = lv;                                 \
        }                                                                     \
    }

#define MFMA_PH(KH)                                                           \
    {                                                                         \
        _Pragma("unroll")                                                     \
        for (int ks = 0; ks < 4; ++ks) {                                      \
            int kA = (KH) * 64 + ks * 16 + ksel * 8;                          \
            int kB = ks * 16 + ksel * 8;                                      \
            int arow = mh * 32 + lr;                                          \
            int au = arow * 128 + (kA ^ ((arow & 7) << 3));                   \
            int brow = ng * 32 + lr;                                          \
            int bu = brow * 64 + (kB ^ ((brow & 7) << 3));                    \
            f16x8 ah = *(const f16x8*)&a_hi[au];                              \
            f16x8 al = *(const f16x8*)&a_lo[au];                              \
            f16x8 bh = *(const f16x8*)&b_hi[bu];                              \
            f16x8 bl = *(const f16x8*)&b_lo[bu];                              \
            acc = __builtin_amdgcn_mfma_f32_32x32x16_f16(ah, bh, acc, 0, 0, 0); \
            acc = __builtin_amdgcn_mfma_f32_32x32x16_f16(al, bh, acc, 0, 0, 0); \
            acc = __builtin_amdgcn_mfma_f32_32x32x16_f16(ah, bl, acc, 0, 0, 0); \
        }                                                                     \
    }

#define BAR_LG   asm volatile("s_waitcnt lgkmcnt(0)" ::: "memory"); __builtin_amdgcn_s_barrier();
#define BAR_LGV  asm volatile("s_waitcnt vmcnt(0) lgkmcnt(0)" ::: "memory"); __builtin_amdgcn_s_barrier();
#define SB0      __builtin_amdgcn_sched_barrier(0);

    // Prologue: B(0,kh0) via gload; gathers tap0; drain; commit A(0)
    GLOADB(0, 0) SB0
    ISSUE_G(0) SB0
    asm volatile("s_waitcnt vmcnt(0)" ::: "memory");
    COMMIT_A(0)
    BAR_LGV

    for (int k = 0; k < 8; ++k) {
        __builtin_amdgcn_s_setprio(1);
        MFMA_PH(0)                          // A(k), B(k,kh0)
        __builtin_amdgcn_s_setprio(0);
        BAR_LG                              // B(kh0) reads done
        GLOADB(k, 1) SB0                    // stage kh1 (async, no VGPR): 4 loads
        ISSUE_G(k + 1) SB0                  // 32 gathers -> 36 outstanding
        asm volatile("s_waitcnt vmcnt(32)" ::: "memory");   // B(kh1) landed
        __builtin_amdgcn_s_barrier();
        __builtin_amdgcn_s_setprio(1);
        MFMA_PH(1)                          // A(k), B(k,kh1)
        __builtin_amdgcn_s_setprio(0);
        BAR_LG                              // all A,B reads done
        GLOADB(k + 1, 0) SB0                // next tap kh0
        COMMIT_A(k + 1)                     // compiler waits gathers only
        BAR_LGV                             // A(k+1) + B(k+1,kh0) visible
    }
    // ---- tail: k = 8 (no next-tap gathers -> vmcnt(0) for kh1) ----
    __builtin_amdgcn_s_setprio(1);
    MFMA_PH(0)
    __builtin_amdgcn_s_setprio(0);
    BAR_LG
    GLOADB(8, 1) SB0
    asm volatile("s_waitcnt vmcnt(0)" ::: "memory");
    __builtin_amdgcn_s_barrier();
    __builtin_amdgcn_s_setprio(1);
    MFMA_PH(1)
    __builtin_amdgcn_s_setprio(0);
    BAR_LG                                  // all LDS reads done before epilogue reuse
#undef GLOADB
#undef ISSUE_G
#undef COMMIT_A
#undef MFMA_PH
#undef BAR_LG
#undef BAR_LGV
#undef SB0

    // Epilogue.  C/D map: col=l&31, row=(r&3)+8*(r>>2)+4*(l>>5)
    int o = ng * 32 + lr;
    float bv = bias[o];
    if (MODE == 0) {
        float* otile = (float*)smem;        // [64][132] f32 = 33,792 B (spans A+B)
#pragma unroll
        for (int q = 0; q < 4; ++q) {
            int pr = mh * 32 + q * 8 + 4 * ksel;
#pragma unroll
            for (int r = 0; r < 4; ++r) {
                float v = acc[q * 4 + r] + bv;
                v = v > 0.f ? v : 0.f;
                otile[(pr + r) * 132 + o] = v;
            }
        }
        __syncthreads();
        float* dst = outT + ((size_t)(b * HW + p0)) * C0;
        for (int i = tid; i < 2048; i += 512) {
            int row = i >> 5, c = i & 31;
            *(f32x4*)&dst[row * 128 + c * 4] = *(const f32x4*)&otile[row * 132 + c * 4];
        }
    } else {
#pragma unroll
        for (int q = 0; q < 4; ++q) {
            int pr = mh * 32 + q * 8 + 4 * ksel;
            size_t base_o = ((size_t)(b * C0 + o)) * HW + p0 + pr;
            f32x4 x4 = *(const f32x4*)(x0 + base_o);
            f32x4 ov;
#pragma unroll
            for (int r = 0; r < 4; ++r) ov[r] = acc[q * 4 + r] + bv + x4[r];
            *(f32x4*)(outF + base_o) = ov;
        }
    }
}

// ---------------------------------------------------------------------------
// Workspace layout (bytes)
constexpr size_t WB_OFF   = 0;            // f32 [B,18,HW]        2,654,208
constexpr size_t WB_WOFFT = 2654208;      // f32 [128][162]          82,944
constexpr size_t WB_W0H   = 2737152;      // f16 [4][128][32]        32,768
constexpr size_t WB_W1H   = 2769920;      // f16 [4][128][128]      131,072
constexpr size_t WB_WDSH  = 2900992;      // f16 swz [2][9][2][8192]  589,824
constexpr size_t WB_WDSL  = 3490816;      // f16 swz                  589,824
constexpr size_t WB_TA    = 4080640;      // f32 [B,HW,128]      18,874,368
constexpr size_t WB_TB    = 22955008;     // f32 [B,HW,128]      18,874,368
// total 41,829,376 B

extern "C" void kernel_launch(void* const* d_in, const int* in_sizes, int n_in,
                              void* d_out, int out_size, void* d_ws, size_t ws_size,
                              hipStream_t stream)
{
    const float* x0      = (const float*)d_in[0];
    const float* x1      = (const float*)d_in[1];
    const float* w_off   = (const float*)d_in[2];
    const float* b_off   = (const float*)d_in[3];
    const float* s1_sc0w = (const float*)d_in[4];
    const float* s1_sc0b = (const float*)d_in[5];
    const float* s1_sc1w = (const float*)d_in[6];
    const float* s1_sc1b = (const float*)d_in[7];
    const float* s1_sh0w = (const float*)d_in[8];
    const float* s1_sh0b = (const float*)d_in[9];
    const float* s1_sh1w = (const float*)d_in[10];
    const float* s1_sh1b = (const float*)d_in[11];
    const float* w_d1    = (const float*)d_in[12];
    const float* b_d1    = (const float*)d_in[13];
    const float* s2_sc0w = (const float*)d_in[14];
    const float* s2_sc0b = (const float*)d_in[15];
    const float* s2_sc1w = (const float*)d_in[16];
    const float* s2_sc1b = (const float*)d_in[17];
    const float* s2_sh0w = (const float*)d_in[18];
    const float* s2_sh0b = (const float*)d_in[19];
    const float* s2_sh1w = (const float*)d_in[20];
    const float* s2_sh1b = (const float*)d_in[21];
    const float* w_d2    = (const float*)d_in[22];
    const float* b_d2    = (const float*)d_in[23];

    char* wsb = (char*)d_ws;
    float* off   = (float*)(wsb + WB_OFF);
    float* wofft = (float*)(wsb + WB_WOFFT);
    u16*   w0h   = (u16*)(wsb + WB_W0H);
    u16*   w1h   = (u16*)(wsb + WB_W1H);
    u16*   wdsh  = (u16*)(wsb + WB_WDSH);
    u16*   wdsl  = (u16*)(wsb + WB_WDSL);
    float* TA    = (float*)(wsb + WB_TA);
    float* TB    = (float*)(wsb + WB_TB);

    k_prep<<<1152, 256, 0, stream>>>(w_off, w_d1, w_d2,
                                     s1_sc0w, s1_sh0w, s2_sc0w, s2_sh0w,
                                     s1_sc1w, s1_sh1w, s2_sc1w, s2_sh1w,
                                     wofft, wdsh, wdsl, w0h, w1h);
    k_conv_off<<<NTILE, 256, 0, stream>>>(x0, wofft, b_off, off);
    // SFT1: x = x0 (channel-major) -> TA (position-major)
    k_sft_mma<0><<<NTILE, 512, 0, stream>>>(x0, nullptr, x1,
                                            w0h, w0h + 4096,
                                            w1h, w1h + 16384,
                                            s1_sc0b, s1_sh0b, s1_sc1b, s1_sh1b, TA);
    // dconv1: gather TA -> relu -> TB (position-major)
    k_deform12<0><<<NTILE, 512, 0, stream>>>(TA, off, wdsh, wdsl, b_d1,
                                             nullptr, nullptr, TB);
    // SFT2: x = TB (position-major) -> TA (position-major)
    k_sft_mma<1><<<NTILE, 512, 0, stream>>>(nullptr, TB, x1,
                                            w0h + 8192, w0h + 12288,
                                            w1h + 32768, w1h + 49152,
                                            s2_sc0b, s2_sh0b, s2_sc1b, s2_sh1b, TA);
    // dconv2: gather TA -> +bias +x0 -> d_out (channel-major)
    k_deform12<1><<<NTILE, 512, 0, stream>>>(TA, off, wdsh + 9 * 16384, wdsl + 9 * 16384,
                                             b_d2, x0, (float*)d_out, nullptr);
}